// Round 19
// baseline (82.858 us; speedup 1.0000x reference)
//
#include <hip/hip_runtime.h>

#define HW2   96
#define NH    12
#define LPIX  (HW2*HW2)      // 9216
#define BATCH 4

typedef __attribute__((ext_vector_type(8))) short bf16x8;
typedef __attribute__((ext_vector_type(4))) float f32x4;

static __device__ __forceinline__ float bf2f(unsigned short u) {
  union { unsigned int i; float f; } v; v.i = ((unsigned int)u) << 16; return v.f;
}
static __device__ __forceinline__ unsigned short f2bf(float f) {
  union { float f; unsigned int i; } v; v.f = f;
  unsigned int r = v.i + 0x7FFF + ((v.i >> 16) & 1);   // round-nearest-even
  return (unsigned short)(r >> 16);
}

// ---- tiny: convert the three weight matrices to bf16 ----------------------
__global__ __launch_bounds__(256) void cvt_w_kernel(
    const float* __restrict__ Wq, const float* __restrict__ Wkv,
    const float* __restrict__ Wp,
    unsigned short* __restrict__ wqb, unsigned short* __restrict__ wkvb,
    unsigned short* __restrict__ wpb) {
  int i = blockIdx.x * 256 + threadIdx.x;
  if (i < 9216)       wqb[i]          = f2bf(Wq[i]);
  else if (i < 27648) wkvb[i - 9216]  = f2bf(Wkv[i - 9216]);
  else if (i < 64512) wpb[i - 27648]  = f2bf(Wp[i - 27648]);
}

// ---- fused Q+KV GEMM, barrier-free, ILP=2 (R14 verbatim) -------------------
__global__ __launch_bounds__(256) void qkv_gemm(
    const float* __restrict__ X,
    const unsigned short* __restrict__ wq, const unsigned short* __restrict__ wkv,
    const float* __restrict__ bq, const float* __restrict__ bkv,
    const float* __restrict__ fqr, const float* __restrict__ fkr,
    const float* __restrict__ fvr,
    unsigned short* __restrict__ Qb, unsigned short* __restrict__ KVb)
{
  const int tid  = threadIdx.x;
  const int r0   = blockIdx.x * 128;
  const int lane = tid & 63, w = tid >> 6;
  const int col  = lane & 15;
  const int koff = (lane >> 4) * 8;
  const int arow0 = r0 + 16 * w + (lane & 15);
  const int rb0   = r0 + 16 * w + 4 * (lane >> 4);

  bf16x8 af[2][3];
  #pragma unroll
  for (int t = 0; t < 2; t++) {
    const float* xr = X + (size_t)(arow0 + 64 * t) * 96;
    float xv[24];
    *(float4*)&xv[0]  = *(const float4*)(xr + koff);
    *(float4*)&xv[4]  = *(const float4*)(xr + koff + 4);
    *(float4*)&xv[8]  = *(const float4*)(xr + koff + 32);
    *(float4*)&xv[12] = *(const float4*)(xr + koff + 36);
    *(float4*)&xv[16] = *(const float4*)(xr + koff + 64);
    *(float4*)&xv[20] = *(const float4*)(xr + koff + 68);
    unsigned short au[24];
    #pragma unroll
    for (int j = 0; j < 24; j++) au[j] = f2bf(xv[j]);
    af[t][0] = *(const bf16x8*)&au[0];
    af[t][1] = *(const bf16x8*)&au[8];
    af[t][2] = *(const bf16x8*)&au[16];
  }

  const float fqr0 = fqr[0] * 0.07216878364870322f;
  const float fkr0 = fkr[0], fvr0 = fvr[0];

  #pragma unroll
  for (int g = 0; g < 6; g++) {
    bf16x8 bw0[3], bw1[3], bw2[3];
    #pragma unroll
    for (int j = 0; j < 3; j++) {
      int nt = g * 3 + j;
      const unsigned short* wrow = (nt < 6)
          ? wq  + (size_t)(nt * 16 + col) * 96 + koff
          : wkv + (size_t)((nt - 6) * 16 + col) * 96 + koff;
      bw0[j] = *(const bf16x8*)(wrow);
      bw1[j] = *(const bf16x8*)(wrow + 32);
      bw2[j] = *(const bf16x8*)(wrow + 64);
    }
    asm volatile("" ::: "memory");

    #pragma unroll
    for (int j = 0; j < 3; j++) {
      int nt = g * 3 + j;
      f32x4 acc[2];
      #pragma unroll
      for (int t = 0; t < 2; t++) {
        f32x4 a = {0.f, 0.f, 0.f, 0.f};
        a = __builtin_amdgcn_mfma_f32_16x16x32_bf16(af[t][0], bw0[j], a, 0, 0, 0);
        a = __builtin_amdgcn_mfma_f32_16x16x32_bf16(af[t][1], bw1[j], a, 0, 0, 0);
        a = __builtin_amdgcn_mfma_f32_16x16x32_bf16(af[t][2], bw2[j], a, 0, 0, 0);
        acc[t] = a;
      }

      if (nt < 6) {
        int u = nt * 16 + col;
        float bias = bq[u];
        #pragma unroll
        for (int t = 0; t < 2; t++)
          #pragma unroll
          for (int i = 0; i < 4; i++)
            Qb[(size_t)(rb0 + 64 * t + i) * 96 + u] = f2bf((acc[t][i] + bias) * fqr0);
      } else {
        int u = (nt - 6) * 16 + col;
        float bias = bkv[u];
        #pragma unroll
        for (int t = 0; t < 2; t++)
          #pragma unroll
          for (int i = 0; i < 4; i++) {
            float s = (i & 1) ? fvr0 : fkr0;   // row parity: even=K, odd=V
            KVb[(size_t)(rb0 + 64 * t + i) * 192 + u] = f2bf((acc[t][i] + bias) * s);
          }
      }
    }
  }
}

// ---- fused attention + proj: K-halo staged in LDS (coalesced full lines),
// V gather issued before score compute (latency hidden under VALU), R14
// quad attention + R14 proj otherwise.
__global__ __launch_bounds__(192, 1) void attnproj_kernel(
    const unsigned short* __restrict__ Qb, const unsigned short* __restrict__ KVb,
    const unsigned short* __restrict__ wp, const float* __restrict__ bp,
    float* __restrict__ Out)
{
  // K halo: 4 rows x 34 cols, per pixel 12 heads stored as 24 16B-slots:
  // slot n = lo-half of head n, slot 12+n = hi-half. Row padded to 208 ush.
  __shared__ unsigned short kbuf[136 * 208];   // 56,576 B
  unsigned short* s_out = kbuf;                // 64*204 ush reused after barrier

  const int tid = threadIdx.x;
  // XCD-chunked swizzle (576 blocks = 8 x 72, bijective)
  const int bid = (blockIdx.x & 7) * 72 + (blockIdx.x >> 3);
  const int b   = bid / 144;
  const int rem = bid % 144;
  const int hp  = rem / 3, wt = rem % 3;
  const int h   = 2 * hp;                     // even, 0..94
  const int w0  = 32 * wt;

  const int n  = tid % NH;
  const int qd = tid / NH;                    // quad 0..15
  const int w  = w0 + 2 * qd;                 // even, <= 94

  // ---- issue Q loads first (oldest in flight; consumed after barrier) ----
  uint4 qA[4], qB[4];
  #pragma unroll
  for (int t = 0; t < 4; t++) {
    int l = (h + (t >> 1)) * HW2 + w + (t & 1);
    const unsigned short* qp = Qb + ((size_t)b * LPIX + l) * 192 + n * 16;
    qA[t] = *(const uint4*)(qp);
    qB[t] = *(const uint4*)(qp + 8);
  }

  // ---- stage K halo: 136 px x 24 chunks = 3264 16B chunks, 17/thread ----
  #pragma unroll
  for (int it = 0; it < 17; it++) {
    int c  = tid + it * 192;
    int px = c / 24, p = c % 24;
    int hr = px / 34, wc = px - hr * 34;
    int hh = min(max(h - 1 + hr, 0), HW2 - 1);
    int ww = min(max(w0 - 1 + wc, 0), HW2 - 1);
    const unsigned short* src =
        KVb + ((size_t)b * 18432 + 2 * (hh * HW2 + ww)) * 192 + p * 8;
    int slot = (p & 1) ? 12 + (p >> 1) : (p >> 1);
    *(uint4*)&kbuf[px * 208 + slot * 8] = *(const uint4*)src;
  }
  __syncthreads();

  {
    const unsigned short* kvb = KVb + (size_t)b * (LPIX * 384) + n * 16;

    // V gather addresses (VALU) + issue ALL V loads, pinned before scores
    int nbo[16];
    #pragma unroll
    for (int hx = 0; hx < 16; hx++) {
      int hh = h + (hx >> 2) - 1;
      int ww = w + (hx & 3) - 1;
      int hc = min(max(hh, 0), HW2 - 1);
      int wc = min(max(ww, 0), HW2 - 1);
      nbo[hx] = (hc * HW2 + wc) * 384;
    }
    const bool rok[4] = { h > 0, true, true, h < HW2 - 2 };

    uint4 vH[16][2];
    #pragma unroll
    for (int hx = 0; hx < 16; hx++) {
      const unsigned short* vp = kvb + nbo[hx] + 192;
      vH[hx][0] = *(const uint4*)(vp);
      vH[hx][1] = *(const uint4*)(vp + 8);
    }
    asm volatile("" ::: "memory");            // V in flight under score compute

    // ---- scores: K from LDS ----
    float sc[4][9];
    bool  okk[4][9];
    #pragma unroll
    for (int t = 0; t < 4; t++) {
      const int tr = t >> 1, tc = t & 1;
      float q[16];
      const unsigned short* qs = (const unsigned short*)&qA[t];
      #pragma unroll
      for (int j = 0; j < 8; j++) q[j] = bf2f(qs[j]);
      qs = (const unsigned short*)&qB[t];
      #pragma unroll
      for (int j = 0; j < 8; j++) q[8 + j] = bf2f(qs[j]);
      #pragma unroll
      for (int kk = 0; kk < 9; kk++) {
        int dr = kk / 3, dc = kk % 3;
        int px = (tr + dr) * 34 + 2 * qd + tc + dc;
        int wcol = w + tc + dc - 1;
        okk[t][kk] = rok[dr + tr] && ((unsigned)wcol < (unsigned)HW2);
        uint4 k0 = *(const uint4*)&kbuf[px * 208 + n * 8];
        uint4 k1 = *(const uint4*)&kbuf[px * 208 + 96 + n * 8];
        float s = 0.f;
        const unsigned short* kd = (const unsigned short*)&k0;
        #pragma unroll
        for (int j = 0; j < 8; j++) s = fmaf(q[j], bf2f(kd[j]), s);
        kd = (const unsigned short*)&k1;
        #pragma unroll
        for (int j = 0; j < 8; j++) s = fmaf(q[8 + j], bf2f(kd[j]), s);
        sc[t][kk] = okk[t][kk] ? s : 0.f;
      }
    }
    __syncthreads();          // K region dead; V drained; s_out may overwrite

    // ---- softmax + PV + s_out ----
    #pragma unroll
    for (int t = 0; t < 4; t++) {
      const int tr = t >> 1, tc = t & 1;
      float m = sc[t][0];
      #pragma unroll
      for (int kk = 1; kk < 9; kk++) m = fmaxf(m, sc[t][kk]);
      float ssum = 0.f;
      #pragma unroll
      for (int kk = 0; kk < 9; kk++) {
        float e = __expf(sc[t][kk] - m);
        sc[t][kk] = e;
        ssum += e;
      }
      float acc[16];
      #pragma unroll
      for (int j = 0; j < 16; j++) acc[j] = 0.f;
      #pragma unroll
      for (int kk = 0; kk < 9; kk++) {
        int hx = (kk / 3 + tr) * 4 + kk % 3 + tc;
        float wgt = okk[t][kk] ? sc[t][kk] : 0.f;
        const unsigned short* vd = (const unsigned short*)&vH[hx][0];
        #pragma unroll
        for (int j = 0; j < 8; j++) acc[j] = fmaf(wgt, bf2f(vd[j]), acc[j]);
        vd = (const unsigned short*)&vH[hx][1];
        #pragma unroll
        for (int j = 0; j < 8; j++) acc[8 + j] = fmaf(wgt, bf2f(vd[j]), acc[8 + j]);
      }
      float rinv = 1.f / ssum;
      unsigned short od[16];
      #pragma unroll
      for (int j = 0; j < 16; j++) od[j] = f2bf(acc[j] * rinv);
      int sr = tr * 32 + 2 * qd + tc;
      unsigned short* op = s_out + sr * 204 + n * 16;
      *(uint4*)(op)     = *(uint4*)&od[0];
      *(uint4*)(op + 8) = *(uint4*)&od[8];
    }
  }
  __syncthreads();

  // ---- proj (R14 verbatim) ----
  const int lane = tid & 63, wv = tid >> 6;    // wv 0..2
  const int col  = lane & 15;
  const int koff = (lane >> 4) * 8;

  bf16x8 af[4][6];
  #pragma unroll
  for (int rg = 0; rg < 4; rg++) {
    int arow = 16 * rg + (lane & 15);
    #pragma unroll
    for (int kt = 0; kt < 6; kt++)
      af[rg][kt] = *(const bf16x8*)&s_out[arow * 204 + koff + kt * 32];
  }

  #pragma unroll
  for (int t4 = 0; t4 < 4; t4++) {
    int nt = wv * 4 + t4;
    const unsigned short* wrow = wp + (size_t)(nt * 16 + col) * 192 + koff;
    bf16x8 bw[6];
    #pragma unroll
    for (int kt = 0; kt < 6; kt++) bw[kt] = *(const bf16x8*)(wrow + kt * 32);
    asm volatile("" ::: "memory");

    int u = nt * 16 + col;
    float bias = bp[u];
    #pragma unroll
    for (int rg = 0; rg < 4; rg++) {
      f32x4 acc = {0.f, 0.f, 0.f, 0.f};
      #pragma unroll
      for (int kt = 0; kt < 6; kt++)
        acc = __builtin_amdgcn_mfma_f32_16x16x32_bf16(af[rg][kt], bw[kt], acc, 0, 0, 0);
      int hh_out = h + (rg >> 1);
      int wbase  = w0 + 16 * (rg & 1) + 4 * (lane >> 4);
      #pragma unroll
      for (int i = 0; i < 4; i++) {
        int row_g = b * LPIX + hh_out * HW2 + wbase + i;
        Out[(size_t)row_g * 192 + u] = acc[i] + bias;
      }
    }
  }
}

extern "C" void kernel_launch(void* const* d_in, const int* in_sizes, int n_in,
                              void* d_out, int out_size, void* d_ws, size_t ws_size,
                              hipStream_t stream) {
  const float* x   = (const float*)d_in[0];
  const float* Wq  = (const float*)d_in[1];
  const float* bq  = (const float*)d_in[2];
  const float* Wkv = (const float*)d_in[3];
  const float* bkv = (const float*)d_in[4];
  const float* Wp  = (const float*)d_in[5];
  const float* bp  = (const float*)d_in[6];
  const float* fqr = (const float*)d_in[7];
  const float* fkr = (const float*)d_in[8];
  const float* fvr = (const float*)d_in[9];

  char* ws = (char*)d_ws;
  unsigned short* Qb   = (unsigned short*)ws;                 // 14,155,776 B
  unsigned short* KVb  = (unsigned short*)(ws + 14155776);    // 28,311,552 B
  unsigned short* wqb  = (unsigned short*)(ws + 42467328);
  unsigned short* wkvb = (unsigned short*)(ws + 42485760);
  unsigned short* wpb  = (unsigned short*)(ws + 42522624);

  cvt_w_kernel<<<dim3(252), dim3(256), 0, stream>>>(Wq, Wkv, Wp, wqb, wkvb, wpb);

  qkv_gemm<<<dim3(576), dim3(256), 0, stream>>>(
      x, wqb, wkvb, bq, bkv, fqr, fkr, fvr, Qb, KVb);

  attnproj_kernel<<<dim3(576), dim3(192), 0, stream>>>(
      Qb, KVb, wpb, bp, (float*)d_out);
}

// Round 20
// 74.043 us; speedup vs baseline: 1.1191x; 1.1191x over previous
//
#include <hip/hip_runtime.h>

#define HW2   96
#define NH    12
#define LPIX  (HW2*HW2)      // 9216
#define BATCH 4

typedef __attribute__((ext_vector_type(8))) short bf16x8;
typedef __attribute__((ext_vector_type(4))) float f32x4;

static __device__ __forceinline__ float bf2f(unsigned short u) {
  union { unsigned int i; float f; } v; v.i = ((unsigned int)u) << 16; return v.f;
}
static __device__ __forceinline__ unsigned short f2bf(float f) {
  union { float f; unsigned int i; } v; v.f = f;
  unsigned int r = v.i + 0x7FFF + ((v.i >> 16) & 1);   // round-nearest-even
  return (unsigned short)(r >> 16);
}
// async global->LDS, 16B per lane, no destination VGPRs (vmcnt-counted)
static __device__ __forceinline__ void gload_lds16(const void* g, void* l) {
  __builtin_amdgcn_global_load_lds(
      (const __attribute__((address_space(1))) void*)g,
      (__attribute__((address_space(3))) void*)l, 16, 0, 0);
}

// ---- tiny: convert the three weight matrices to bf16 ----------------------
__global__ __launch_bounds__(256) void cvt_w_kernel(
    const float* __restrict__ Wq, const float* __restrict__ Wkv,
    const float* __restrict__ Wp,
    unsigned short* __restrict__ wqb, unsigned short* __restrict__ wkvb,
    unsigned short* __restrict__ wpb) {
  int i = blockIdx.x * 256 + threadIdx.x;
  if (i < 9216)       wqb[i]          = f2bf(Wq[i]);
  else if (i < 27648) wkvb[i - 9216]  = f2bf(Wkv[i - 9216]);
  else if (i < 64512) wpb[i - 27648]  = f2bf(Wp[i - 27648]);
}

// ---- fused Q+KV GEMM, barrier-free, ILP=2 (R14 verbatim) -------------------
__global__ __launch_bounds__(256) void qkv_gemm(
    const float* __restrict__ X,
    const unsigned short* __restrict__ wq, const unsigned short* __restrict__ wkv,
    const float* __restrict__ bq, const float* __restrict__ bkv,
    const float* __restrict__ fqr, const float* __restrict__ fkr,
    const float* __restrict__ fvr,
    unsigned short* __restrict__ Qb, unsigned short* __restrict__ KVb)
{
  const int tid  = threadIdx.x;
  const int r0   = blockIdx.x * 128;
  const int lane = tid & 63, w = tid >> 6;
  const int col  = lane & 15;
  const int koff = (lane >> 4) * 8;
  const int arow0 = r0 + 16 * w + (lane & 15);
  const int rb0   = r0 + 16 * w + 4 * (lane >> 4);

  bf16x8 af[2][3];
  #pragma unroll
  for (int t = 0; t < 2; t++) {
    const float* xr = X + (size_t)(arow0 + 64 * t) * 96;
    float xv[24];
    *(float4*)&xv[0]  = *(const float4*)(xr + koff);
    *(float4*)&xv[4]  = *(const float4*)(xr + koff + 4);
    *(float4*)&xv[8]  = *(const float4*)(xr + koff + 32);
    *(float4*)&xv[12] = *(const float4*)(xr + koff + 36);
    *(float4*)&xv[16] = *(const float4*)(xr + koff + 64);
    *(float4*)&xv[20] = *(const float4*)(xr + koff + 68);
    unsigned short au[24];
    #pragma unroll
    for (int j = 0; j < 24; j++) au[j] = f2bf(xv[j]);
    af[t][0] = *(const bf16x8*)&au[0];
    af[t][1] = *(const bf16x8*)&au[8];
    af[t][2] = *(const bf16x8*)&au[16];
  }

  const float fqr0 = fqr[0] * 0.07216878364870322f;
  const float fkr0 = fkr[0], fvr0 = fvr[0];

  #pragma unroll
  for (int g = 0; g < 6; g++) {
    bf16x8 bw0[3], bw1[3], bw2[3];
    #pragma unroll
    for (int j = 0; j < 3; j++) {
      int nt = g * 3 + j;
      const unsigned short* wrow = (nt < 6)
          ? wq  + (size_t)(nt * 16 + col) * 96 + koff
          : wkv + (size_t)((nt - 6) * 16 + col) * 96 + koff;
      bw0[j] = *(const bf16x8*)(wrow);
      bw1[j] = *(const bf16x8*)(wrow + 32);
      bw2[j] = *(const bf16x8*)(wrow + 64);
    }
    asm volatile("" ::: "memory");

    #pragma unroll
    for (int j = 0; j < 3; j++) {
      int nt = g * 3 + j;
      f32x4 acc[2];
      #pragma unroll
      for (int t = 0; t < 2; t++) {
        f32x4 a = {0.f, 0.f, 0.f, 0.f};
        a = __builtin_amdgcn_mfma_f32_16x16x32_bf16(af[t][0], bw0[j], a, 0, 0, 0);
        a = __builtin_amdgcn_mfma_f32_16x16x32_bf16(af[t][1], bw1[j], a, 0, 0, 0);
        a = __builtin_amdgcn_mfma_f32_16x16x32_bf16(af[t][2], bw2[j], a, 0, 0, 0);
        acc[t] = a;
      }

      if (nt < 6) {
        int u = nt * 16 + col;
        float bias = bq[u];
        #pragma unroll
        for (int t = 0; t < 2; t++)
          #pragma unroll
          for (int i = 0; i < 4; i++)
            Qb[(size_t)(rb0 + 64 * t + i) * 96 + u] = f2bf((acc[t][i] + bias) * fqr0);
      } else {
        int u = (nt - 6) * 16 + col;
        float bias = bkv[u];
        #pragma unroll
        for (int t = 0; t < 2; t++)
          #pragma unroll
          for (int i = 0; i < 4; i++) {
            float s = (i & 1) ? fvr0 : fkr0;   // row parity: even=K, odd=V
            KVb[(size_t)(rb0 + 64 * t + i) * 192 + u] = f2bf((acc[t][i] + bias) * s);
          }
      }
    }
  }
}

// ---- fused attention + proj: K-halo staged via global_load_lds (async,
// zero-VGPR), V register-gather hidden under score compute, R14 otherwise.
__global__ __launch_bounds__(192, 1) void attnproj_kernel(
    const unsigned short* __restrict__ Qb, const unsigned short* __restrict__ KVb,
    const unsigned short* __restrict__ wp, const float* __restrict__ bp,
    float* __restrict__ Out)
{
  // K halo: 136 px x 192 ush (contiguous, no padding - required by
  // global_load_lds). Head n of pixel px at kbuf[px*192 + n*16].
  __shared__ __align__(16) unsigned short kbuf[136 * 192];  // 52,224 B
  unsigned short* s_out = kbuf;               // 64*204 ush reused after barrier

  const int tid = threadIdx.x;
  // XCD-chunked swizzle (576 blocks = 8 x 72, bijective)
  const int bid = (blockIdx.x & 7) * 72 + (blockIdx.x >> 3);
  const int b   = bid / 144;
  const int rem = bid % 144;
  const int hp  = rem / 3, wt = rem % 3;
  const int h   = 2 * hp;                     // even, 0..94
  const int w0  = 32 * wt;

  const int lane = tid & 63;
  const int wv   = tid >> 6;                  // wave 0..2
  const int n    = tid % NH;
  const int qd   = tid / NH;                  // quad 0..15
  const int w    = w0 + 2 * qd;               // even, <= 94

  // ---- issue Q loads first (drained by the staging barrier) ----
  uint4 qA[4], qB[4];
  #pragma unroll
  for (int t = 0; t < 4; t++) {
    int l = (h + (t >> 1)) * HW2 + w + (t & 1);
    const unsigned short* qp = Qb + ((size_t)b * LPIX + l) * 192 + n * 16;
    qA[t] = *(const uint4*)(qp);
    qB[t] = *(const uint4*)(qp + 8);
  }

  // ---- stage K halo: 136 px x 24 chunks(16B) = 3264 chunks = 51 wave-insts,
  // 17 per wave; LDS dest contiguous per inst, global addr per-lane (clamped).
  {
    const unsigned short* kbase = KVb + (size_t)b * 18432 * 192;
    #pragma unroll
    for (int c = 0; c < 17; c++) {
      int j  = wv * 17 + c;                   // wave-inst index 0..50
      int ch = j * 64 + lane;                 // chunk 0..3263
      int px = ch / 24, part = ch - px * 24;
      int hr = px / 34, wc = px - hr * 34;
      int hh = min(max(h - 1 + hr, 0), HW2 - 1);
      int ww = min(max(w0 - 1 + wc, 0), HW2 - 1);
      const unsigned short* src = kbase + (size_t)(2 * (hh * HW2 + ww)) * 192 + part * 8;
      gload_lds16(src, &kbuf[(size_t)j * 512]);   // 512 ush = 64 lanes x 8
    }
  }
  __syncthreads();                            // vmcnt(0): K staged, Q arrived

  {
    const unsigned short* kvb = KVb + (size_t)b * (LPIX * 384) + n * 16;

    // V gather addresses + issue ALL V loads (latency hides under scores)
    int nbo[16];
    #pragma unroll
    for (int hx = 0; hx < 16; hx++) {
      int hh = h + (hx >> 2) - 1;
      int ww = w + (hx & 3) - 1;
      int hc = min(max(hh, 0), HW2 - 1);
      int wc = min(max(ww, 0), HW2 - 1);
      nbo[hx] = (hc * HW2 + wc) * 384;
    }
    const bool rok[4] = { h > 0, true, true, h < HW2 - 2 };

    uint4 vH[16][2];
    #pragma unroll
    for (int hx = 0; hx < 16; hx++) {
      const unsigned short* vp = kvb + nbo[hx] + 192;
      vH[hx][0] = *(const uint4*)(vp);
      vH[hx][1] = *(const uint4*)(vp + 8);
    }
    asm volatile("" ::: "memory");            // V in flight under score compute

    // ---- scores: K from LDS ----
    float sc[4][9];
    bool  okk[4][9];
    #pragma unroll
    for (int t = 0; t < 4; t++) {
      const int tr = t >> 1, tc = t & 1;
      float q[16];
      const unsigned short* qs = (const unsigned short*)&qA[t];
      #pragma unroll
      for (int j = 0; j < 8; j++) q[j] = bf2f(qs[j]);
      qs = (const unsigned short*)&qB[t];
      #pragma unroll
      for (int j = 0; j < 8; j++) q[8 + j] = bf2f(qs[j]);
      #pragma unroll
      for (int kk = 0; kk < 9; kk++) {
        int dr = kk / 3, dc = kk % 3;
        int px = (tr + dr) * 34 + 2 * qd + tc + dc;
        int wcol = w + tc + dc - 1;
        okk[t][kk] = rok[dr + tr] && ((unsigned)wcol < (unsigned)HW2);
        uint4 k0 = *(const uint4*)&kbuf[px * 192 + n * 16];
        uint4 k1 = *(const uint4*)&kbuf[px * 192 + n * 16 + 8];
        float s = 0.f;
        const unsigned short* kd = (const unsigned short*)&k0;
        #pragma unroll
        for (int j = 0; j < 8; j++) s = fmaf(q[j], bf2f(kd[j]), s);
        kd = (const unsigned short*)&k1;
        #pragma unroll
        for (int j = 0; j < 8; j++) s = fmaf(q[8 + j], bf2f(kd[j]), s);
        sc[t][kk] = okk[t][kk] ? s : 0.f;
      }
    }
    __syncthreads();          // K region dead; s_out may overwrite

    // ---- softmax + PV + s_out ----
    #pragma unroll
    for (int t = 0; t < 4; t++) {
      const int tr = t >> 1, tc = t & 1;
      float m = sc[t][0];
      #pragma unroll
      for (int kk = 1; kk < 9; kk++) m = fmaxf(m, sc[t][kk]);
      float ssum = 0.f;
      #pragma unroll
      for (int kk = 0; kk < 9; kk++) {
        float e = __expf(sc[t][kk] - m);
        sc[t][kk] = e;
        ssum += e;
      }
      float acc[16];
      #pragma unroll
      for (int j = 0; j < 16; j++) acc[j] = 0.f;
      #pragma unroll
      for (int kk = 0; kk < 9; kk++) {
        int hx = (kk / 3 + tr) * 4 + kk % 3 + tc;
        float wgt = okk[t][kk] ? sc[t][kk] : 0.f;
        const unsigned short* vd = (const unsigned short*)&vH[hx][0];
        #pragma unroll
        for (int j = 0; j < 8; j++) acc[j] = fmaf(wgt, bf2f(vd[j]), acc[j]);
        vd = (const unsigned short*)&vH[hx][1];
        #pragma unroll
        for (int j = 0; j < 8; j++) acc[8 + j] = fmaf(wgt, bf2f(vd[j]), acc[8 + j]);
      }
      float rinv = 1.f / ssum;
      unsigned short od[16];
      #pragma unroll
      for (int j = 0; j < 16; j++) od[j] = f2bf(acc[j] * rinv);
      int sr = tr * 32 + 2 * qd + tc;
      unsigned short* op = s_out + sr * 204 + n * 16;
      *(uint4*)(op)     = *(uint4*)&od[0];
      *(uint4*)(op + 8) = *(uint4*)&od[8];
    }
  }
  __syncthreads();

  // ---- proj (R14 verbatim) ----
  const int col  = lane & 15;
  const int koff = (lane >> 4) * 8;

  bf16x8 af[4][6];
  #pragma unroll
  for (int rg = 0; rg < 4; rg++) {
    int arow = 16 * rg + (lane & 15);
    #pragma unroll
    for (int kt = 0; kt < 6; kt++)
      af[rg][kt] = *(const bf16x8*)&s_out[arow * 204 + koff + kt * 32];
  }

  #pragma unroll
  for (int t4 = 0; t4 < 4; t4++) {
    int nt = wv * 4 + t4;
    const unsigned short* wrow = wp + (size_t)(nt * 16 + col) * 192 + koff;
    bf16x8 bw[6];
    #pragma unroll
    for (int kt = 0; kt < 6; kt++) bw[kt] = *(const bf16x8*)(wrow + kt * 32);
    asm volatile("" ::: "memory");

    int u = nt * 16 + col;
    float bias = bp[u];
    #pragma unroll
    for (int rg = 0; rg < 4; rg++) {
      f32x4 acc = {0.f, 0.f, 0.f, 0.f};
      #pragma unroll
      for (int kt = 0; kt < 6; kt++)
        acc = __builtin_amdgcn_mfma_f32_16x16x32_bf16(af[rg][kt], bw[kt], acc, 0, 0, 0);
      int hh_out = h + (rg >> 1);
      int wbase  = w0 + 16 * (rg & 1) + 4 * (lane >> 4);
      #pragma unroll
      for (int i = 0; i < 4; i++) {
        int row_g = b * LPIX + hh_out * HW2 + wbase + i;
        Out[(size_t)row_g * 192 + u] = acc[i] + bias;
      }
    }
  }
}

extern "C" void kernel_launch(void* const* d_in, const int* in_sizes, int n_in,
                              void* d_out, int out_size, void* d_ws, size_t ws_size,
                              hipStream_t stream) {
  const float* x   = (const float*)d_in[0];
  const float* Wq  = (const float*)d_in[1];
  const float* bq  = (const float*)d_in[2];
  const float* Wkv = (const float*)d_in[3];
  const float* bkv = (const float*)d_in[4];
  const float* Wp  = (const float*)d_in[5];
  const float* bp  = (const float*)d_in[6];
  const float* fqr = (const float*)d_in[7];
  const float* fkr = (const float*)d_in[8];
  const float* fvr = (const float*)d_in[9];

  char* ws = (char*)d_ws;
  unsigned short* Qb   = (unsigned short*)ws;                 // 14,155,776 B
  unsigned short* KVb  = (unsigned short*)(ws + 14155776);    // 28,311,552 B
  unsigned short* wqb  = (unsigned short*)(ws + 42467328);
  unsigned short* wkvb = (unsigned short*)(ws + 42485760);
  unsigned short* wpb  = (unsigned short*)(ws + 42522624);

  cvt_w_kernel<<<dim3(252), dim3(256), 0, stream>>>(Wq, Wkv, Wp, wqb, wkvb, wpb);

  qkv_gemm<<<dim3(576), dim3(256), 0, stream>>>(
      x, wqb, wkvb, bq, bkv, fqr, fkr, fvr, Qb, KVb);

  attnproj_kernel<<<dim3(576), dim3(192), 0, stream>>>(
      Qb, KVb, wpb, bp, (float*)d_out);
}

// Round 21
// 63.570 us; speedup vs baseline: 1.3034x; 1.1647x over previous
//
#include <hip/hip_runtime.h>

#define HW2   96
#define NH    12
#define LPIX  (HW2*HW2)      // 9216
#define BATCH 4

typedef __attribute__((ext_vector_type(8))) short bf16x8;
typedef __attribute__((ext_vector_type(4))) float f32x4;

static __device__ __forceinline__ float bf2f(unsigned short u) {
  union { unsigned int i; float f; } v; v.i = ((unsigned int)u) << 16; return v.f;
}
static __device__ __forceinline__ unsigned short f2bf(float f) {
  union { float f; unsigned int i; } v; v.f = f;
  unsigned int r = v.i + 0x7FFF + ((v.i >> 16) & 1);   // round-nearest-even
  return (unsigned short)(r >> 16);
}

// ---- tiny: convert the three weight matrices to bf16 ----------------------
__global__ __launch_bounds__(256) void cvt_w_kernel(
    const float* __restrict__ Wq, const float* __restrict__ Wkv,
    const float* __restrict__ Wp,
    unsigned short* __restrict__ wqb, unsigned short* __restrict__ wkvb,
    unsigned short* __restrict__ wpb) {
  int i = blockIdx.x * 256 + threadIdx.x;
  if (i < 9216)       wqb[i]          = f2bf(Wq[i]);
  else if (i < 27648) wkvb[i - 9216]  = f2bf(Wkv[i - 9216]);
  else if (i < 64512) wpb[i - 27648]  = f2bf(Wp[i - 27648]);
}

// ---- fused Q+KV GEMM, barrier-free, ILP=2 (R14 verbatim) -------------------
__global__ __launch_bounds__(256) void qkv_gemm(
    const float* __restrict__ X,
    const unsigned short* __restrict__ wq, const unsigned short* __restrict__ wkv,
    const float* __restrict__ bq, const float* __restrict__ bkv,
    const float* __restrict__ fqr, const float* __restrict__ fkr,
    const float* __restrict__ fvr,
    unsigned short* __restrict__ Qb, unsigned short* __restrict__ KVb)
{
  const int tid  = threadIdx.x;
  const int r0   = blockIdx.x * 128;
  const int lane = tid & 63, w = tid >> 6;
  const int col  = lane & 15;
  const int koff = (lane >> 4) * 8;
  const int arow0 = r0 + 16 * w + (lane & 15);
  const int rb0   = r0 + 16 * w + 4 * (lane >> 4);

  bf16x8 af[2][3];
  #pragma unroll
  for (int t = 0; t < 2; t++) {
    const float* xr = X + (size_t)(arow0 + 64 * t) * 96;
    float xv[24];
    *(float4*)&xv[0]  = *(const float4*)(xr + koff);
    *(float4*)&xv[4]  = *(const float4*)(xr + koff + 4);
    *(float4*)&xv[8]  = *(const float4*)(xr + koff + 32);
    *(float4*)&xv[12] = *(const float4*)(xr + koff + 36);
    *(float4*)&xv[16] = *(const float4*)(xr + koff + 64);
    *(float4*)&xv[20] = *(const float4*)(xr + koff + 68);
    unsigned short au[24];
    #pragma unroll
    for (int j = 0; j < 24; j++) au[j] = f2bf(xv[j]);
    af[t][0] = *(const bf16x8*)&au[0];
    af[t][1] = *(const bf16x8*)&au[8];
    af[t][2] = *(const bf16x8*)&au[16];
  }

  const float fqr0 = fqr[0] * 0.07216878364870322f;
  const float fkr0 = fkr[0], fvr0 = fvr[0];

  #pragma unroll
  for (int g = 0; g < 6; g++) {
    bf16x8 bw0[3], bw1[3], bw2[3];
    #pragma unroll
    for (int j = 0; j < 3; j++) {
      int nt = g * 3 + j;
      const unsigned short* wrow = (nt < 6)
          ? wq  + (size_t)(nt * 16 + col) * 96 + koff
          : wkv + (size_t)((nt - 6) * 16 + col) * 96 + koff;
      bw0[j] = *(const bf16x8*)(wrow);
      bw1[j] = *(const bf16x8*)(wrow + 32);
      bw2[j] = *(const bf16x8*)(wrow + 64);
    }
    asm volatile("" ::: "memory");

    #pragma unroll
    for (int j = 0; j < 3; j++) {
      int nt = g * 3 + j;
      f32x4 acc[2];
      #pragma unroll
      for (int t = 0; t < 2; t++) {
        f32x4 a = {0.f, 0.f, 0.f, 0.f};
        a = __builtin_amdgcn_mfma_f32_16x16x32_bf16(af[t][0], bw0[j], a, 0, 0, 0);
        a = __builtin_amdgcn_mfma_f32_16x16x32_bf16(af[t][1], bw1[j], a, 0, 0, 0);
        a = __builtin_amdgcn_mfma_f32_16x16x32_bf16(af[t][2], bw2[j], a, 0, 0, 0);
        acc[t] = a;
      }

      if (nt < 6) {
        int u = nt * 16 + col;
        float bias = bq[u];
        #pragma unroll
        for (int t = 0; t < 2; t++)
          #pragma unroll
          for (int i = 0; i < 4; i++)
            Qb[(size_t)(rb0 + 64 * t + i) * 96 + u] = f2bf((acc[t][i] + bias) * fqr0);
      } else {
        int u = (nt - 6) * 16 + col;
        float bias = bkv[u];
        #pragma unroll
        for (int t = 0; t < 2; t++)
          #pragma unroll
          for (int i = 0; i < 4; i++) {
            float s = (i & 1) ? fvr0 : fkr0;   // row parity: even=K, odd=V
            KVb[(size_t)(rb0 + 64 * t + i) * 192 + u] = f2bf((acc[t][i] + bias) * s);
          }
      }
    }
  }
}

// ---- fused attention + proj (R14 verbatim) ---------------------------------
__global__ __launch_bounds__(192, 1) void attnproj_kernel(
    const unsigned short* __restrict__ Qb, const unsigned short* __restrict__ KVb,
    const unsigned short* __restrict__ wp, const float* __restrict__ bp,
    float* __restrict__ Out)
{
  __shared__ unsigned short s_out[64 * 204];
  const int tid = threadIdx.x;
  // XCD-chunked swizzle (576 blocks = 8 x 72, bijective)
  const int bid = (blockIdx.x & 7) * 72 + (blockIdx.x >> 3);
  const int b   = bid / 144;
  const int rem = bid % 144;
  const int hp  = rem / 3, wt = rem % 3;
  const int h   = 2 * hp;                     // even, 0..94
  const int w0  = 32 * wt;

  {
    const int n  = tid % NH;
    const int qd = tid / NH;                  // quad 0..15
    const int w  = w0 + 2 * qd;               // even, <= 94

    const unsigned short* kvb = KVb + (size_t)b * (LPIX * 384) + n * 16;

    int nbo[16];
    #pragma unroll
    for (int hx = 0; hx < 16; hx++) {
      int hh = h + (hx >> 2) - 1;
      int ww = w + (hx & 3) - 1;
      int hc = min(max(hh, 0), HW2 - 1);
      int wc = min(max(ww, 0), HW2 - 1);
      nbo[hx] = (hc * HW2 + wc) * 384;
    }
    const bool rok[4] = { h > 0, true, true, h < HW2 - 2 };

    uint4 kH[16][2];
    #pragma unroll
    for (int hx = 0; hx < 16; hx++) {
      const unsigned short* kp = kvb + nbo[hx];
      kH[hx][0] = *(const uint4*)(kp);
      kH[hx][1] = *(const uint4*)(kp + 8);
    }
    uint4 qA[4], qB[4];
    #pragma unroll
    for (int t = 0; t < 4; t++) {
      int l = (h + (t >> 1)) * HW2 + w + (t & 1);
      const unsigned short* qp = Qb + ((size_t)b * LPIX + l) * 192 + n * 16;
      qA[t] = *(const uint4*)(qp);
      qB[t] = *(const uint4*)(qp + 8);
    }
    asm volatile("" ::: "memory");

    float sc[4][9];
    bool  okk[4][9];
    #pragma unroll
    for (int t = 0; t < 4; t++) {
      const int tr = t >> 1, tc = t & 1;
      float q[16];
      const unsigned short* qs = (const unsigned short*)&qA[t];
      #pragma unroll
      for (int j = 0; j < 8; j++) q[j] = bf2f(qs[j]);
      qs = (const unsigned short*)&qB[t];
      #pragma unroll
      for (int j = 0; j < 8; j++) q[8 + j] = bf2f(qs[j]);
      #pragma unroll
      for (int kk = 0; kk < 9; kk++) {
        int dr = kk / 3, dc = kk % 3;
        int hx = (dr + tr) * 4 + dc + tc;
        int wcol = w + tc + dc - 1;
        okk[t][kk] = rok[dr + tr] && ((unsigned)wcol < (unsigned)HW2);
        float s = 0.f;
        const unsigned short* kd = (const unsigned short*)&kH[hx][0];
        #pragma unroll
        for (int j = 0; j < 8; j++) s = fmaf(q[j], bf2f(kd[j]), s);
        kd = (const unsigned short*)&kH[hx][1];
        #pragma unroll
        for (int j = 0; j < 8; j++) s = fmaf(q[8 + j], bf2f(kd[j]), s);
        sc[t][kk] = okk[t][kk] ? s : 0.f;
      }
    }

    uint4 vH[16][2];
    #pragma unroll
    for (int hx = 0; hx < 16; hx++) {
      const unsigned short* vp = kvb + nbo[hx] + 192;
      vH[hx][0] = *(const uint4*)(vp);
      vH[hx][1] = *(const uint4*)(vp + 8);
    }
    asm volatile("" ::: "memory");

    #pragma unroll
    for (int t = 0; t < 4; t++) {
      const int tr = t >> 1, tc = t & 1;
      float m = sc[t][0];
      #pragma unroll
      for (int kk = 1; kk < 9; kk++) m = fmaxf(m, sc[t][kk]);
      float ssum = 0.f;
      #pragma unroll
      for (int kk = 0; kk < 9; kk++) {
        float e = __expf(sc[t][kk] - m);
        sc[t][kk] = e;
        ssum += e;
      }
      float acc[16];
      #pragma unroll
      for (int j = 0; j < 16; j++) acc[j] = 0.f;
      #pragma unroll
      for (int kk = 0; kk < 9; kk++) {
        int hx = (kk / 3 + tr) * 4 + kk % 3 + tc;
        float wgt = okk[t][kk] ? sc[t][kk] : 0.f;
        const unsigned short* vd = (const unsigned short*)&vH[hx][0];
        #pragma unroll
        for (int j = 0; j < 8; j++) acc[j] = fmaf(wgt, bf2f(vd[j]), acc[j]);
        vd = (const unsigned short*)&vH[hx][1];
        #pragma unroll
        for (int j = 0; j < 8; j++) acc[8 + j] = fmaf(wgt, bf2f(vd[j]), acc[8 + j]);
      }
      float rinv = 1.f / ssum;
      unsigned short od[16];
      #pragma unroll
      for (int j = 0; j < 16; j++) od[j] = f2bf(acc[j] * rinv);
      int sr = tr * 32 + 2 * qd + tc;
      unsigned short* op = s_out + sr * 204 + n * 16;
      *(uint4*)(op)     = *(uint4*)&od[0];
      *(uint4*)(op + 8) = *(uint4*)&od[8];
    }
  }
  __syncthreads();

  const int lane = tid & 63, wv = tid >> 6;    // wv 0..2
  const int col  = lane & 15;
  const int koff = (lane >> 4) * 8;

  bf16x8 af[4][6];
  #pragma unroll
  for (int rg = 0; rg < 4; rg++) {
    int arow = 16 * rg + (lane & 15);
    #pragma unroll
    for (int kt = 0; kt < 6; kt++)
      af[rg][kt] = *(const bf16x8*)&s_out[arow * 204 + koff + kt * 32];
  }

  #pragma unroll
  for (int t4 = 0; t4 < 4; t4++) {
    int nt = wv * 4 + t4;
    const unsigned short* wrow = wp + (size_t)(nt * 16 + col) * 192 + koff;
    bf16x8 bw[6];
    #pragma unroll
    for (int kt = 0; kt < 6; kt++) bw[kt] = *(const bf16x8*)(wrow + kt * 32);
    asm volatile("" ::: "memory");

    int u = nt * 16 + col;
    float bias = bp[u];
    #pragma unroll
    for (int rg = 0; rg < 4; rg++) {
      f32x4 acc = {0.f, 0.f, 0.f, 0.f};
      #pragma unroll
      for (int kt = 0; kt < 6; kt++)
        acc = __builtin_amdgcn_mfma_f32_16x16x32_bf16(af[rg][kt], bw[kt], acc, 0, 0, 0);
      int hh_out = h + (rg >> 1);
      int wbase  = w0 + 16 * (rg & 1) + 4 * (lane >> 4);
      #pragma unroll
      for (int i = 0; i < 4; i++) {
        int row_g = b * LPIX + hh_out * HW2 + wbase + i;
        Out[(size_t)row_g * 192 + u] = acc[i] + bias;
      }
    }
  }
}

extern "C" void kernel_launch(void* const* d_in, const int* in_sizes, int n_in,
                              void* d_out, int out_size, void* d_ws, size_t ws_size,
                              hipStream_t stream) {
  const float* x   = (const float*)d_in[0];
  const float* Wq  = (const float*)d_in[1];
  const float* bq  = (const float*)d_in[2];
  const float* Wkv = (const float*)d_in[3];
  const float* bkv = (const float*)d_in[4];
  const float* Wp  = (const float*)d_in[5];
  const float* bp  = (const float*)d_in[6];
  const float* fqr = (const float*)d_in[7];
  const float* fkr = (const float*)d_in[8];
  const float* fvr = (const float*)d_in[9];

  char* ws = (char*)d_ws;
  unsigned short* Qb   = (unsigned short*)ws;                 // 14,155,776 B
  unsigned short* KVb  = (unsigned short*)(ws + 14155776);    // 28,311,552 B
  unsigned short* wqb  = (unsigned short*)(ws + 42467328);
  unsigned short* wkvb = (unsigned short*)(ws + 42485760);
  unsigned short* wpb  = (unsigned short*)(ws + 42522624);

  cvt_w_kernel<<<dim3(252), dim3(256), 0, stream>>>(Wq, Wkv, Wp, wqb, wkvb, wpb);

  qkv_gemm<<<dim3(576), dim3(256), 0, stream>>>(
      x, wqb, wkvb, bq, bkv, fqr, fkr, fvr, Qb, KVb);

  attnproj_kernel<<<dim3(576), dim3(192), 0, stream>>>(
      Qb, KVb, wpb, bp, (float*)d_out);
}